// Round 2
// baseline (320.473 us; speedup 1.0000x reference)
//
#include <hip/hip_runtime.h>
#include <stdint.h>

#define IN_F   4096
#define OUT_F  4096
#define BATCH  4096

#define BM 128
#define BN 128
#define BK 32

typedef __bf16 bf16x8 __attribute__((ext_vector_type(8)));
typedef float  f32x4  __attribute__((ext_vector_type(4)));
typedef unsigned short u16x8 __attribute__((ext_vector_type(8)));

// ---------- fp32 -> bf16 (round-to-nearest-even) ----------
__device__ inline unsigned short f32_to_bf16_rne(float f) {
    unsigned int u = __float_as_uint(f);
    u += 0x7FFFu + ((u >> 16) & 1u);
    return (unsigned short)(u >> 16);
}

// One kernel converts BOTH x and W. 8 elems/thread: 2x float4 load, 1x 16B store.
__global__ void cvt2_f32_bf16(const float4* __restrict__ xa,
                              const float4* __restrict__ wa,
                              u16x8* __restrict__ xo,
                              u16x8* __restrict__ wo, int n8_per) {
    int i = blockIdx.x * blockDim.x + threadIdx.x;
    const float4* src;
    u16x8* dst;
    if (i < n8_per) { src = xa; dst = xo; }
    else            { src = wa; dst = wo; i -= n8_per; }
    float4 v0 = src[2 * i];
    float4 v1 = src[2 * i + 1];
    u16x8 o;
    o[0] = f32_to_bf16_rne(v0.x); o[1] = f32_to_bf16_rne(v0.y);
    o[2] = f32_to_bf16_rne(v0.z); o[3] = f32_to_bf16_rne(v0.w);
    o[4] = f32_to_bf16_rne(v1.x); o[5] = f32_to_bf16_rne(v1.y);
    o[6] = f32_to_bf16_rne(v1.z); o[7] = f32_to_bf16_rne(v1.w);
    dst[i] = o;
}

// ---------- async global->LDS, 16B per lane ----------
__device__ inline void async_load16(const void* g, void* l) {
    __builtin_amdgcn_global_load_lds(
        (const __attribute__((address_space(1))) unsigned int*)g,
        (__attribute__((address_space(3))) unsigned int*)l,
        16, 0, 0);
}

// ---------- m97-structure bf16 GEMM + XOR bank swizzle: C = A * Bt^T + bias ----------
// LDS layout per 16B chunk: row r, k-chunk c (8 elems) stored at slot (c ^ (r&3)).
// Staging side: lane l (srow=l>>2, cs=l&3) DMAs global chunk (cs ^ (srow&3)) so
// LDS[16*l] = row srow, chunk cs-swizzled. Read side applies the same XOR.
// Breaks the 8-way b128 conflict (row stride 64B => banks (fr&1)*16 only) down
// to a free 2-way alias (m136).
__global__ void gemm_bt_bf16(const unsigned short* __restrict__ A,
                             const unsigned short* __restrict__ Bt,
                             const float* __restrict__ bias,
                             float* __restrict__ out) {
    __shared__ unsigned short lsA[BM * BK];  // 8 KB
    __shared__ unsigned short lsB[BN * BK];  // 8 KB

    const int tid  = threadIdx.x;
    const int lane = tid & 63;
    const int wv   = tid >> 6;          // wave 0..3
    const int wm   = (wv & 1) * 64;     // wave M offset within tile
    const int wn   = (wv >> 1) * 64;    // wave N offset within tile

    const int m0 = blockIdx.y * BM;
    const int n0 = blockIdx.x * BN;

    // Staging: lane l -> LDS base + 16*l. srow = l>>2 (0..15), chunk slot = l&3.
    // Global chunk fetched = (l&3) ^ (srow&3)  [XOR swizzle].
    const int srow = lane >> 2;                      // 0..15
    const int scol = (((lane & 3) ^ (srow & 3)) * 8); // swizzled 8-elem chunk

    const unsigned short* gA0 = A  + (size_t)(m0 + wv * 32 + srow) * IN_F + scol;
    const unsigned short* gA1 = gA0 + 16 * (size_t)IN_F;  // (srow+16)&3 == srow&3
    const unsigned short* gB0 = Bt + (size_t)(n0 + wv * 32 + srow) * IN_F + scol;
    const unsigned short* gB1 = gB0 + 16 * (size_t)IN_F;

    unsigned short* lA0 = &lsA[(wv * 32)      * BK];
    unsigned short* lA1 = &lsA[(wv * 32 + 16) * BK];
    unsigned short* lB0 = &lsB[(wv * 32)      * BK];
    unsigned short* lB1 = &lsB[(wv * 32 + 16) * BK];

    // MFMA A/B-operand layout: row = lane&15, k = (lane>>4)*8 + j
    const int fr = lane & 15;
    const int kc = lane >> 4;                 // k-chunk 0..3
    const int slot = (kc ^ (fr & 3)) * 8;     // swizzled read slot (elems)

    f32x4 acc[4][4] = {};

    for (int kt = 0; kt < IN_F; kt += BK) {
        async_load16(gA0, lA0);
        async_load16(gA1, lA1);
        async_load16(gB0, lB0);
        async_load16(gB1, lB1);
        gA0 += BK; gA1 += BK; gB0 += BK; gB1 += BK;
        __syncthreads();

        bf16x8 aF[4], bF[4];
        #pragma unroll
        for (int i = 0; i < 4; ++i)   // (wm+i*16+fr)&3 == fr&3, swizzle consistent
            aF[i] = *(const bf16x8*)&lsA[(wm + i * 16 + fr) * BK + slot];
        #pragma unroll
        for (int j = 0; j < 4; ++j)
            bF[j] = *(const bf16x8*)&lsB[(wn + j * 16 + fr) * BK + slot];

        #pragma unroll
        for (int i = 0; i < 4; ++i)
            #pragma unroll
            for (int j = 0; j < 4; ++j)
                acc[i][j] = __builtin_amdgcn_mfma_f32_16x16x32_bf16(
                    aF[i], bF[j], acc[i][j], 0, 0, 0);
        __syncthreads();
    }

    // Epilogue. C/D layout (m89/m91): col = lane&15, row = (lane>>4)*4 + reg
    const int ocol = n0 + wn;
    float bj[4];
    #pragma unroll
    for (int j = 0; j < 4; ++j) bj[j] = bias[ocol + j * 16 + fr];

    const int rsel = (lane >> 4) * 4;
    #pragma unroll
    for (int i = 0; i < 4; ++i) {
        #pragma unroll
        for (int v = 0; v < 4; ++v) {
            const int row = m0 + wm + i * 16 + rsel + v;
            float* orow = out + (size_t)row * OUT_F + ocol + fr;
            #pragma unroll
            for (int j = 0; j < 4; ++j)
                orow[j * 16] = acc[i][j][v] + bj[j];
        }
    }
}

// ---------- fallback: correct fp32 tiled GEMM (only if ws too small) ----------
__global__ void fb_gemm(const float* __restrict__ A, const float* __restrict__ W,
                        const float* __restrict__ bias, float* __restrict__ out) {
    __shared__ float tA[16][17];
    __shared__ float tW[16][17];
    const int tx = threadIdx.x, ty = threadIdx.y;
    const int row = blockIdx.y * 16 + ty;
    const int col = blockIdx.x * 16 + tx;
    float s = 0.f;
    for (int k = 0; k < IN_F; k += 16) {
        tA[ty][tx] = A[(size_t)row * IN_F + k + tx];
        tW[ty][tx] = W[(size_t)(blockIdx.x * 16 + ty) * IN_F + k + tx];
        __syncthreads();
        #pragma unroll
        for (int kk = 0; kk < 16; ++kk) s += tA[ty][kk] * tW[tx][kk];
        __syncthreads();
    }
    out[(size_t)row * OUT_F + col] = s + bias[col];
}

extern "C" void kernel_launch(void* const* d_in, const int* in_sizes, int n_in,
                              void* d_out, int out_size, void* d_ws, size_t ws_size,
                              hipStream_t stream) {
    const float* x = (const float*)d_in[0];
    const float* W = (const float*)d_in[1];
    const float* b = (const float*)d_in[2];
    float* out = (float*)d_out;

    const size_t elems      = (size_t)BATCH * IN_F;  // 16.7M per matrix
    const size_t bf16_bytes = elems * 2;             // 32 MiB each

    if (ws_size >= 2 * bf16_bytes) {
        unsigned short* xb = (unsigned short*)d_ws;
        unsigned short* wb = (unsigned short*)((char*)d_ws + bf16_bytes);

        const int n8_per = (int)(elems / 8);             // 2,097,152
        const int threads = 2 * n8_per;
        cvt2_f32_bf16<<<(threads + 255) / 256, 256, 0, stream>>>(
            (const float4*)x, (const float4*)W, (u16x8*)xb, (u16x8*)wb, n8_per);

        dim3 grid(OUT_F / BN, BATCH / BM);  // 32 x 32
        gemm_bt_bf16<<<grid, 256, 0, stream>>>(xb, wb, b, out);
    } else {
        dim3 grid(OUT_F / 16, BATCH / 16);
        fb_gemm<<<grid, dim3(16, 16), 0, stream>>>(x, W, b, out);
    }
}